// Round 1
// 10158.242 us; speedup vs baseline: 1.8274x; 1.8274x over previous
//
#include <hip/hip_runtime.h>

#define NB    40
#define RC    128
#define SC    256
#define BATCH 4
#define TLEN  16384
#define TSKIP 4096
#define TT    64

// ---------------------------------------------------------------------------
// One-time weight transform: [oc][ic](k) -> [ic][oc] so inner-loop weight
// loads are contiguous in oc (scalar-load friendly).
//   w0T/w1T/wresT : [NB][128][128]  (ic-major)
//   wskipT        : [NB][128][256]  (ic-major)
// ---------------------------------------------------------------------------
__global__ void wtrans_kernel(const float* __restrict__ w_dil,
                              const float* __restrict__ w_res,
                              const float* __restrict__ w_skip,
                              float* __restrict__ w0T, float* __restrict__ w1T,
                              float* __restrict__ wresT, float* __restrict__ wskipT)
{
    int idx = blockIdx.x * blockDim.x + threadIdx.x;
    const int n_dil  = NB * RC * RC;   // 655360
    const int n_skip = NB * RC * SC;   // 1310720
    if (idx < n_dil) {
        int i  = idx / (RC * RC);
        int r  = idx - i * RC * RC;
        int ic = r / RC;
        int oc = r - ic * RC;
        size_t s = (size_t)(i * RC + oc) * RC + ic;
        w0T[idx]   = w_dil[s * 2 + 0];
        w1T[idx]   = w_dil[s * 2 + 1];
        wresT[idx] = w_res[s];
    }
    if (idx < n_skip) {
        int i  = idx / (RC * SC);
        int r  = idx - i * RC * SC;
        int ic = r / SC;
        int oc = r - ic * SC;
        wskipT[idx] = w_skip[(size_t)(i * SC + oc) * RC + ic];
    }
}

// ---------------------------------------------------------------------------
// One residual block. Restructured (R2): one wave <-> one oc-group so the
// weight address is WAVE-UNIFORM -> compiler emits s_load (scalar cache,
// SGPR broadcast) instead of per-lane VMEM float4 reloads at L2 latency.
// Tile: 64 timesteps (lanes) x 128 channels. 4 waves, each owns 32 oc.
// ---------------------------------------------------------------------------
__global__ __launch_bounds__(256, 2) void layer_kernel(
    const float* __restrict__ src, float* __restrict__ dst,
    float* __restrict__ skip_out,
    const float* __restrict__ w0T, const float* __restrict__ w1T,
    const float* __restrict__ wresT, const float* __restrict__ wskipT,
    int dilation)
{
    __shared__ float Xs0[RC][TT];   // tap t-d; becomes G after conv phase
    __shared__ float Xs1[RC][TT];   // tap t (also the residual input)

    const int tid  = threadIdx.x;
    const int lane = tid & 63;                                   // timestep
    const int wid  = __builtin_amdgcn_readfirstlane(tid >> 6);   // uniform 0..3
    const int b    = blockIdx.y;
    const int t0   = blockIdx.x * TT;

    const float* srcb = src + (size_t)b * RC * TLEN;

    // ---- stage input tiles ------------------------------------------------
    // Each wave stages 32 rows; a wave-pass covers 4 rows x 16 float4 cols.
    const int rbase = wid * 32;
    const int srow  = lane >> 4;          // 0..3
    const int scol  = (lane & 15) * 4;    // 0,4,..,60

    #pragma unroll
    for (int it = 0; it < 8; ++it) {
        int row = rbase + it * 4 + srow;
        const float* p = srcb + (size_t)row * TLEN + t0 + scol;
        *(float4*)&Xs1[row][scol] = *(const float4*)p;
    }
    if (t0 >= dilation && (dilation & 3) == 0) {
        // fast path: shifted tap fully in-bounds and 16B-aligned (d multiple of 4)
        #pragma unroll
        for (int it = 0; it < 8; ++it) {
            int row = rbase + it * 4 + srow;
            const float* p = srcb + (size_t)row * TLEN + t0 + scol - dilation;
            *(float4*)&Xs0[row][scol] = *(const float4*)p;
        }
    } else {
        #pragma unroll
        for (int it = 0; it < 8; ++it) {
            int row = rbase + it * 4 + srow;
            #pragma unroll
            for (int e = 0; e < 4; ++e) {
                int tg = t0 + scol + e - dilation;
                Xs0[row][scol + e] = (tg >= 0) ? srcb[(size_t)row * TLEN + tg] : 0.0f;
            }
        }
    }
    __syncthreads();

    // ---- dilated conv: H[oc][t], oc = wid*32 .. wid*32+31 ----
    const int ocb = wid * 32;             // wave-uniform
    float acc[32];
    #pragma unroll
    for (int j = 0; j < 32; ++j) acc[j] = 0.0f;

    #pragma unroll 1
    for (int k = 0; k < RC; ++k) {
        float x0 = Xs0[k][lane];
        float x1 = Xs1[k][lane];
        const float* __restrict__ w0p = w0T + (k * RC + ocb);  // uniform addr
        const float* __restrict__ w1p = w1T + (k * RC + ocb);  // uniform addr
        #pragma unroll
        for (int j = 0; j < 32; ++j) {
            acc[j] += w0p[j] * x0 + w1p[j] * x1;
        }
    }
    __syncthreads();   // all reads of Xs0 done before overwrite

    // gated = tanh(h) * sigmoid(h) -> G (in Xs0's storage)
    #pragma unroll
    for (int j = 0; j < 32; ++j) {
        float h  = acc[j];
        float gv = tanhf(h) * (1.0f / (1.0f + __expf(-h)));
        Xs0[ocb + j][lane] = gv;
    }
    __syncthreads();

    // ---- residual 1x1: dst = Wres@G + X1 ----
    float racc[32];
    #pragma unroll
    for (int j = 0; j < 32; ++j) racc[j] = 0.0f;

    #pragma unroll 2
    for (int k = 0; k < RC; ++k) {
        float gv = Xs0[k][lane];
        const float* __restrict__ wrp = wresT + (k * RC + ocb);  // uniform
        #pragma unroll
        for (int j = 0; j < 32; ++j) racc[j] += wrp[j] * gv;
    }
    float* dstb = dst + (size_t)b * RC * TLEN;
    #pragma unroll
    for (int j = 0; j < 32; ++j) {
        dstb[(size_t)(ocb + j) * TLEN + t0 + lane] = racc[j] + Xs1[ocb + j][lane];
    }

    // ---- skip 1x1 (only last TSKIP timesteps): 64 oc per wave, 2 halves ----
    if (t0 >= TLEN - TSKIP) {
        float* skipb = skip_out + (size_t)b * SC * TSKIP;
        const int ts = t0 - (TLEN - TSKIP) + lane;
        #pragma unroll 1
        for (int half = 0; half < 2; ++half) {
            const int scb = wid * 64 + half * 32;   // wave-uniform
            float sacc[32];
            #pragma unroll
            for (int j = 0; j < 32; ++j) sacc[j] = 0.0f;

            #pragma unroll 2
            for (int k = 0; k < RC; ++k) {
                float gv = Xs0[k][lane];
                const float* __restrict__ wsp = wskipT + (k * SC + scb);  // uniform
                #pragma unroll
                for (int j = 0; j < 32; ++j) sacc[j] += wsp[j] * gv;
            }
            #pragma unroll
            for (int j = 0; j < 32; ++j) {
                skipb[(size_t)(scb + j) * TSKIP + ts] = sacc[j];
            }
        }
    }
}

// ---------------------------------------------------------------------------
extern "C" void kernel_launch(void* const* d_in, const int* in_sizes, int n_in,
                              void* d_out, int out_size, void* d_ws, size_t ws_size,
                              hipStream_t stream)
{
    const float* x      = (const float*)d_in[0];
    const float* w_dil  = (const float*)d_in[1];
    const float* w_res  = (const float*)d_in[2];
    const float* w_skip = (const float*)d_in[3];
    float* out = (float*)d_out;

    // workspace layout (floats): bufA | bufB | w0T | w1T | wresT | wskipT
    float* bufA   = (float*)d_ws;
    float* bufB   = bufA  + (size_t)BATCH * RC * TLEN;
    float* w0T    = bufB  + (size_t)BATCH * RC * TLEN;
    float* w1T    = w0T   + (size_t)NB * RC * RC;
    float* wresT  = w1T   + (size_t)NB * RC * RC;
    float* wskipT = wresT + (size_t)NB * RC * RC;

    wtrans_kernel<<<(NB * RC * SC + 255) / 256, 256, 0, stream>>>(
        w_dil, w_res, w_skip, w0T, w1T, wresT, wskipT);

    for (int i = 0; i < NB; ++i) {
        int d = 1 << (i % 10);
        const float* src = (i == 0) ? x : ((i & 1) ? bufA : bufB);
        float*       dst = (i & 1) ? bufB : bufA;
        float* skip = out + (size_t)i * BATCH * SC * TSKIP;
        dim3 grid(TLEN / TT, BATCH);
        layer_kernel<<<grid, 256, 0, stream>>>(
            src, dst, skip,
            w0T + (size_t)i * RC * RC, w1T + (size_t)i * RC * RC,
            wresT + (size_t)i * RC * RC, wskipT + (size_t)i * RC * SC, d);
    }
}